// Round 1
// baseline (38600.455 us; speedup 1.0000x reference)
//
#include <hip/hip_runtime.h>

// ============================================================================
// GRU autoencoder, single persistent kernel, MI355X (gfx950).
//
// Architecture:
//   grid = 256 blocks x 256 threads, all co-resident. Custom flag barrier
//   (per-block epoch flags, agent-scope atomics) sequences 2054 "epochs":
//     e=1            : prep (pack weights into fp16 hi/lo MFMA-fragment layout)
//     e=2..1026      : encoder ticks u=0..1024  (enc0 computes h0[u], enc1 h1[u-1])
//     e=1027         : z = h1[1023] @ e_lW^T + e_lb
//     e=1028         : gxc = z @ d_Wih0^T + d_bih0   (constant decoder input)
//     e=1029..2054   : decoder ticks v=0..1025  (dec0 g0[v], dec1 g1[v-1],
//                      final linear out[v-2] fused into blocks 0..63)
//   Blocks 0..127  ("P0"): enc0 then dec0 (+ final linear). Task = (rb,hcb):
//   one 16-row x 16-hcol tile, all gates; K split across the 4 waves, LDS
//   reduction, wave0 does the gate nonlinearity epilogue and keeps the fp32
//   h-state tile in registers across all timesteps.
//   Blocks 128..255 ("P1"): enc1 then dec1 (folded [x|h] K=1024 GEMM).
//
// Numerics: fp16 MFMA, weights split into hi+lo fp16 planes (2 MFMA passes,
//   ~fp32 weight fidelity); activations rounded to fp16 once per step (rings);
//   state, gates, biases, z/gxc, output all fp32.
// Coherence: rings/flags/z/gxc via relaxed agent-scope atomics (bypass
//   per-XCD L2) -> no cache invalidation, weights stay L2-resident.
// ============================================================================

#define SC_AGT __HIP_MEMORY_SCOPE_AGENT

typedef _Float16 half8 __attribute__((ext_vector_type(8)));
typedef float floatx4 __attribute__((ext_vector_type(4)));

union H8 { unsigned long long q[2]; half8 h; uint4 u4; };
union HU { _Float16 f; unsigned short u; };

// ---- workspace layout (bytes) ----
static constexpr size_t OFF_FLAGS = 0;                       // 256 * 4
static constexpr size_t OFF_Z     = 4096;                    // 64*128*4
static constexpr size_t OFF_GXC   = OFF_Z + 64 * 128 * 4;    // 64*1536*4
static constexpr size_t OFF_H0    = OFF_GXC + 64 * 1536 * 4; // 2*64*512*2 each
static constexpr size_t OFF_H1    = OFF_H0 + 2 * 64 * 512 * 2;
static constexpr size_t OFF_G0    = OFF_H1 + 2 * 64 * 512 * 2;
static constexpr size_t OFF_G1    = OFF_G0 + 2 * 64 * 512 * 2;
static constexpr size_t OFF_LWP   = OFF_G1 + 2 * 64 * 512 * 2; // 64*512*2
static constexpr size_t OFF_WF    = OFF_LWP + 64 * 512 * 2;
// W-fragment store: unit = (gate,hcb,kc) = 2KB (hi plane 1KB + lo plane 1KB)
// layer unit counts: L0 1728, L1 3072, L2 1536, L3 3072  (total ~18.4 MB)

static constexpr int E_PREP    = 1;
static constexpr int E_ENC_BEG = 2;     // u = e-2, u in [0,1024]
static constexpr int E_ENC_END = 1026;
static constexpr int E_Z       = 1027;
static constexpr int E_GXC     = 1028;
static constexpr int E_DEC_BEG = 1029;  // v = e-1029, v in [0,1025]
static constexpr int E_LAST    = 2054;

__device__ __forceinline__ unsigned long long ald64(const void* p) {
  return __hip_atomic_load((const unsigned long long*)p, __ATOMIC_RELAXED, SC_AGT);
}
__device__ __forceinline__ void ast16(void* p, unsigned short v) {
  __hip_atomic_store((unsigned short*)p, v, __ATOMIC_RELAXED, SC_AGT);
}
__device__ __forceinline__ void ast32u(void* p, unsigned int v) {
  __hip_atomic_store((unsigned int*)p, v, __ATOMIC_RELAXED, SC_AGT);
}
__device__ __forceinline__ void astf(float* p, float v) {
  __hip_atomic_store(p, v, __ATOMIC_RELAXED, SC_AGT);
}

__device__ __forceinline__ float sigm(float x) { return 1.f / (1.f + __expf(-x)); }
__device__ __forceinline__ float tanh_f(float x) {
  x = fminf(fmaxf(x, -30.f), 30.f);
  const float e2 = __expf(2.f * x);
  return (e2 - 1.f) / (e2 + 1.f);
}

#define MFMA(a, b, c) __builtin_amdgcn_mfma_f32_16x16x32_f16((a), (b), (c), 0, 0, 0)

// full-grid barrier wait: every wave polls all 256 block flags (2 x 8B / lane)
__device__ __forceinline__ void pollwait(const int* flags, int target) {
  const int lane = threadIdx.x & 63;
  const unsigned long long* f64 = (const unsigned long long*)flags;
  for (;;) {
    const unsigned long long q0 = ald64(f64 + lane * 2);
    const unsigned long long q1 = ald64(f64 + lane * 2 + 1);
    const bool ok = ((int)(unsigned int)(q0 & 0xffffffffu) >= target) &&
                    ((int)(unsigned int)(q0 >> 32) >= target) &&
                    ((int)(unsigned int)(q1 & 0xffffffffu) >= target) &&
                    ((int)(unsigned int)(q1 >> 32) >= target);
    if (__ballot(ok) == ~0ull) break;
    __builtin_amdgcn_s_sleep(2);
  }
  asm volatile("" ::: "memory");
}

// One GRU step partial-GEMM for this wave's K-slice. Accumulates the 4 gate
// tiles (r, z, xn, hn) over fold-kc range [kc0, kc0+kccnt). Fold region
// [0,hsplit) is the x-side (from xs fp32 or ax fp16 ring), [hsplit,..) is the
// h-side (ah ring, valid only if hvalid). Writes partials to LDS.
__device__ __forceinline__ void tick_partials(
    const char* __restrict__ wf,
    int g0u, int g1u, int g2u, int g3u,
    int nk0, int nk1, int nk2, int nk3,
    int kc0, int kccnt, int hsplit,
    const float* __restrict__ xs,
    const _Float16* __restrict__ ax,
    const _Float16* __restrict__ ah,
    bool hvalid, int hcb, int lane,
    float* __restrict__ partsW) {
  const int quad = lane >> 4;
  H8 A[8];
#pragma unroll
  for (int c = 0; c < 8; ++c) {
    A[c].q[0] = 0ull;
    A[c].q[1] = 0ull;
    if (c < kccnt) {
      const int kc = kc0 + c;
      if (kc < hsplit) {
        if (xs) {
          const float* p = xs + kc * 32 + quad * 8;
          const float4 f0 = *(const float4*)p;
          const float4 f1 = *(const float4*)(p + 4);
          H8 t;
          t.h[0] = (_Float16)f0.x; t.h[1] = (_Float16)f0.y;
          t.h[2] = (_Float16)f0.z; t.h[3] = (_Float16)f0.w;
          t.h[4] = (_Float16)f1.x; t.h[5] = (_Float16)f1.y;
          t.h[6] = (_Float16)f1.z; t.h[7] = (_Float16)f1.w;
          A[c] = t;
        } else {
          const _Float16* p = ax + kc * 32 + quad * 8;
          A[c].q[0] = ald64(p);
          A[c].q[1] = ald64(p + 4);
        }
      } else if (hvalid) {
        const _Float16* p = ah + (kc - hsplit) * 32 + quad * 8;
        A[c].q[0] = ald64(p);
        A[c].q[1] = ald64(p + 4);
      }
    }
  }
  floatx4 ar = {0.f, 0.f, 0.f, 0.f};
  floatx4 az = ar, axn = ar, ahn = ar;
  const size_t lb = (size_t)lane * 16;
#pragma unroll
  for (int c = 0; c < 8; ++c) {
    if (c < kccnt) {
      const int kc = kc0 + c;
      const bool inH = (kc >= hsplit);
      if (!inH || hvalid) {
        {
          const char* b = wf + (size_t)(g0u + hcb * nk0 + kc) * 2048 + lb;
          H8 whi, wlo;
          whi.u4 = *(const uint4*)b;
          wlo.u4 = *(const uint4*)(b + 1024);
          ar = MFMA(A[c].h, whi.h, ar);
          ar = MFMA(A[c].h, wlo.h, ar);
        }
        {
          const char* b = wf + (size_t)(g1u + hcb * nk1 + kc) * 2048 + lb;
          H8 whi, wlo;
          whi.u4 = *(const uint4*)b;
          wlo.u4 = *(const uint4*)(b + 1024);
          az = MFMA(A[c].h, whi.h, az);
          az = MFMA(A[c].h, wlo.h, az);
        }
        if (!inH) {
          const char* b = wf + (size_t)(g2u + hcb * nk2 + kc) * 2048 + lb;
          H8 whi, wlo;
          whi.u4 = *(const uint4*)b;
          wlo.u4 = *(const uint4*)(b + 1024);
          axn = MFMA(A[c].h, whi.h, axn);
          axn = MFMA(A[c].h, wlo.h, axn);
        } else {
          const char* b = wf + (size_t)(g3u + hcb * nk3 + (kc - hsplit)) * 2048 + lb;
          H8 whi, wlo;
          whi.u4 = *(const uint4*)b;
          wlo.u4 = *(const uint4*)(b + 1024);
          ahn = MFMA(A[c].h, whi.h, ahn);
          ahn = MFMA(A[c].h, wlo.h, ahn);
        }
      }
    }
  }
  const int m = lane & 15;
#pragma unroll
  for (int i = 0; i < 4; ++i) {
    const int idx = (quad * 4 + i) * 16 + m;
    partsW[0 * 256 + idx] = ar[i];
    partsW[1 * 256 + idx] = az[i];
    partsW[2 * 256 + idx] = axn[i];
    partsW[3 * 256 + idx] = ahn[i];
  }
}

// wave0: reduce the 4 waves' partials, apply GRU gate math, update fp32
// register state, store fp16 h tile to the broadcast ring.
__device__ __forceinline__ void gru_epilogue(
    const float (*__restrict__ P)[4][256],
    int quad, int m, int rb, int hcb,
    float br, float bz, float bx, float bh,
    bool dec0, const float* gxr, const float* gxz, const float* gxn,
    float* hold, _Float16* __restrict__ ring) {
#pragma unroll
  for (int i = 0; i < 4; ++i) {
    const int idx = (quad * 4 + i) * 16 + m;
    const float sr = P[0][0][idx] + P[1][0][idx] + P[2][0][idx] + P[3][0][idx];
    const float sz = P[0][1][idx] + P[1][1][idx] + P[2][1][idx] + P[3][1][idx];
    const float sx = P[0][2][idx] + P[1][2][idx] + P[2][2][idx] + P[3][2][idx];
    const float sh = P[0][3][idx] + P[1][3][idx] + P[2][3][idx] + P[3][3][idx];
    float pr, pz, px;
    if (dec0) { pr = sr + gxr[i] + br; pz = sz + gxz[i] + bz; px = gxn[i]; }
    else      { pr = sr + br;          pz = sz + bz;          px = sx + bx; }
    const float r = sigm(pr);
    const float z = sigm(pz);
    const float n = tanh_f(px + r * (sh + bh));
    const float hh = (1.f - z) * n + z * hold[i];
    hold[i] = hh;
    HU cv;
    cv.f = (_Float16)hh;
    ast16(ring + (rb * 16 + quad * 4 + i) * 512 + hcb * 16 + m, cv.u);
  }
}

extern "C" __global__ void __launch_bounds__(256, 1) gru_ae_kernel(
    const float* __restrict__ x,
    const float* __restrict__ eW0i, const float* __restrict__ eW0h,
    const float* __restrict__ eb0i, const float* __restrict__ eb0h,
    const float* __restrict__ eW1i, const float* __restrict__ eW1h,
    const float* __restrict__ eb1i, const float* __restrict__ eb1h,
    const float* __restrict__ elW, const float* __restrict__ elb,
    const float* __restrict__ dW0i, const float* __restrict__ dW0h,
    const float* __restrict__ db0i, const float* __restrict__ db0h,
    const float* __restrict__ dW1i, const float* __restrict__ dW1h,
    const float* __restrict__ db1i, const float* __restrict__ db1h,
    const float* __restrict__ dlW, const float* __restrict__ dlb,
    float* __restrict__ out, char* __restrict__ ws) {
  const int tid = threadIdx.x, bid = blockIdx.x;
  const int lane = tid & 63, w = tid >> 6;
  const int quad = lane >> 4, m = lane & 15;
  const bool isP0 = bid < 128;
  const int pb = isP0 ? bid : bid - 128;
  const int rb = pb >> 5, hcb = pb & 31;

  int* flags = (int*)(ws + OFF_FLAGS);
  float* zbuf = (float*)(ws + OFF_Z);
  float* gxc = (float*)(ws + OFF_GXC);
  _Float16* h0r = (_Float16*)(ws + OFF_H0);
  _Float16* h1r = (_Float16*)(ws + OFF_H1);
  _Float16* g0r = (_Float16*)(ws + OFF_G0);
  _Float16* g1r = (_Float16*)(ws + OFF_G1);
  _Float16* lWp = (_Float16*)(ws + OFF_LWP);
  const char* wfb = ws + OFF_WF;
  const char* wf0 = wfb;
  const char* wf1 = wfb + (size_t)1728 * 2048;
  const char* wf2 = wfb + (size_t)(1728 + 3072) * 2048;
  const char* wf3 = wfb + (size_t)(1728 + 3072 + 1536) * 2048;

  __shared__ float parts[4][4][256];
  __shared__ float outp[4][64];

  float hold[4] = {0.f, 0.f, 0.f, 0.f};
  float br = 0.f, bz = 0.f, bx = 0.f, bh = 0.f;
  float gxr[4] = {0, 0, 0, 0}, gxz[4] = {0, 0, 0, 0}, gxn[4] = {0, 0, 0, 0};

  for (int e = E_PREP; e <= E_LAST; ++e) {
    if (e > E_PREP) pollwait(flags, e - 1);

    // ---------------- WORK (all waves) ----------------
    if (e == E_PREP) {
      // pack weights: fp16 hi/lo planes, MFMA-fragment ordered
      const int uend[4] = {1728, 4800, 6336, 9408};
      const int gub_[4][4] = {{0, 576, 1152, 1216}, {0, 1024, 2048, 2560},
                              {0, 512, 1024, 1024}, {0, 1024, 2048, 2560}};
      const int nkc_[4][4] = {{18, 18, 2, 16}, {32, 32, 16, 16},
                              {16, 16, 0, 16}, {32, 32, 16, 16}};
      const size_t wbL[4] = {0, (size_t)1728 * 2048, (size_t)4800 * 2048,
                             (size_t)6336 * 2048};
      const int wgid = bid * 4 + w;
      for (int unit = wgid; unit < 9408; unit += 1024) {
        int L = 0, lu = unit;
        if (unit >= uend[2]) { L = 3; lu = unit - uend[2]; }
        else if (unit >= uend[1]) { L = 2; lu = unit - uend[1]; }
        else if (unit >= uend[0]) { L = 1; lu = unit - uend[0]; }
        int g;
        if (lu < gub_[L][1]) g = 0;
        else if (lu < gub_[L][2]) g = 1;
        else if (nkc_[L][2] > 0 && lu < gub_[L][3]) g = 2;
        else g = 3;
        const int r2 = lu - gub_[L][g];
        const int nk = nkc_[L][g];
        const int hcbp = r2 / nk, kcp = r2 % nk;
        const int colp = hcbp * 16 + m;
        const float *Wi, *Wh;
        int Din;
        if (L == 0)      { Wi = eW0i; Wh = eW0h; Din = 64; }
        else if (L == 1) { Wi = eW1i; Wh = eW1h; Din = 512; }
        else if (L == 2) { Wi = nullptr; Wh = dW0h; Din = 0; }
        else             { Wi = dW1i; Wh = dW1h; Din = 512; }
        char* ub = (char*)(ws + OFF_WF) + wbL[L] + (size_t)lu * 2048 + lane * 16;
#pragma unroll
        for (int jj = 0; jj < 4; ++jj) {
          unsigned int hiw = 0, low = 0;
#pragma unroll
          for (int j2 = 0; j2 < 2; ++j2) {
            const int j = jj * 2 + j2;
            const int k = kcp * 32 + quad * 8 + j;
            float wv;
            if (g <= 1) {
              if (Wi && k < Din) wv = Wi[(size_t)(g * 512 + colp) * Din + k];
              else wv = Wh[(size_t)(g * 512 + colp) * 512 + (k - (Wi ? Din : 0))];
            } else if (g == 2) {
              wv = Wi[(size_t)(1024 + colp) * Din + k];
            } else {
              wv = Wh[(size_t)(1024 + colp) * 512 + k];
            }
            HU hi, lo;
            hi.f = (_Float16)wv;
            lo.f = (_Float16)(wv - (float)hi.f);
            hiw |= ((unsigned int)hi.u) << (16 * j2);
            low |= ((unsigned int)lo.u) << (16 * j2);
          }
          ast32u(ub + jj * 4, hiw);
          ast32u(ub + 1024 + jj * 4, low);
        }
      }
      // pack final-linear weight fp16
      const int gid = bid * 256 + tid;
      if (gid < 32768) {
        HU cv;
        cv.f = (_Float16)dlW[gid];
        ast16(lWp + gid, cv.u);
      }
    } else if (e <= E_ENC_END) {
      const int u = e - E_ENC_BEG;
      if (e == E_ENC_BEG) {
        const int colg = hcb * 16 + m;
        if (isP0) {
          br = eb0i[colg] + eb0h[colg];
          bz = eb0i[512 + colg] + eb0h[512 + colg];
          bx = eb0i[1024 + colg];
          bh = eb0h[1024 + colg];
        } else {
          br = eb1i[colg] + eb1h[colg];
          bz = eb1i[512 + colg] + eb1h[512 + colg];
          bx = eb1i[1024 + colg];
          bh = eb1h[1024 + colg];
        }
        hold[0] = hold[1] = hold[2] = hold[3] = 0.f;
      }
      if (isP0) {
        if (u <= 1023) {
          const int t = u;
          const float* xs = x + ((size_t)t * 64 + rb * 16 + m) * 64;
          const _Float16* ah = h0r + (size_t)((t - 1) & 1) * 32768 + (rb * 16 + m) * 512;
          const int kc0 = (w == 0) ? 0 : (w == 1) ? 5 : (w == 2) ? 10 : 14;
          const int cnt = (w < 2) ? 5 : 4;
          tick_partials(wf0, 0, 576, 1152, 1216, 18, 18, 2, 16, kc0, cnt, 2,
                        xs, nullptr, ah, t >= 1, hcb, lane, &parts[w][0][0]);
        }
      } else {
        if (u >= 1) {
          const int t = u - 1;
          const _Float16* ax = h0r + (size_t)(t & 1) * 32768 + (rb * 16 + m) * 512;
          const _Float16* ah = h1r + (size_t)((t - 1) & 1) * 32768 + (rb * 16 + m) * 512;
          tick_partials(wf1, 0, 1024, 2048, 2560, 32, 32, 16, 16, w * 8, 8, 16,
                        nullptr, ax, ah, t >= 1, hcb, lane, &parts[w][0][0]);
        }
      }
    } else if (e == E_Z) {
      const int b = bid >> 2, e0 = (bid & 3) * 32;
      float acc = 0.f;
      if (lane < 32) {
        const _Float16* hsrc = h1r + (size_t)1 * 32768 + b * 512;  // h1[1023]
        const float* lwrow = elW + (size_t)(e0 + lane) * 512;
        for (int ch = 0; ch < 16; ++ch) {
          const int k = w * 128 + ch * 8;
          H8 a;
          a.q[0] = ald64(hsrc + k);
          a.q[1] = ald64(hsrc + k + 4);
          const float4 l0 = *(const float4*)(lwrow + k);
          const float4 l1 = *(const float4*)(lwrow + k + 4);
          acc += (float)a.h[0] * l0.x + (float)a.h[1] * l0.y +
                 (float)a.h[2] * l0.z + (float)a.h[3] * l0.w +
                 (float)a.h[4] * l1.x + (float)a.h[5] * l1.y +
                 (float)a.h[6] * l1.z + (float)a.h[7] * l1.w;
        }
      }
      outp[w][lane] = acc;
    } else if (e == E_GXC) {
      const int b = bid & 63, cb = (bid >> 6) * 384;
      for (int idx = w * 64 + lane; idx < 384; idx += 256) {
        const int c = cb + idx;
        float acc = db0i[c];
        const float* zr = zbuf + b * 128;
        const float* wr = dW0i + (size_t)c * 128;
        for (int k = 0; k < 128; ++k) acc += zr[k] * wr[k];
        astf(&gxc[(size_t)b * 1536 + c], acc);
      }
    } else {
      const int v = e - E_DEC_BEG;
      if (e == E_DEC_BEG) {
        const int colg = hcb * 16 + m;
        if (isP0) {
          br = db0h[colg];
          bz = db0h[512 + colg];
          bx = 0.f;
          bh = db0h[1024 + colg];
#pragma unroll
          for (int i = 0; i < 4; ++i) {
            const int row = rb * 16 + quad * 4 + i;
            gxr[i] = gxc[(size_t)row * 1536 + colg];
            gxz[i] = gxc[(size_t)row * 1536 + 512 + colg];
            gxn[i] = gxc[(size_t)row * 1536 + 1024 + colg];
          }
        } else {
          br = db1i[colg] + db1h[colg];
          bz = db1i[512 + colg] + db1h[512 + colg];
          bx = db1i[1024 + colg];
          bh = db1h[1024 + colg];
        }
        hold[0] = hold[1] = hold[2] = hold[3] = 0.f;
      }
      if (isP0) {
        if (v <= 1023) {
          const int t = v;
          const _Float16* ah = g0r + (size_t)((t - 1) & 1) * 32768 + (rb * 16 + m) * 512;
          tick_partials(wf2, 0, 512, 0, 1024, 16, 16, 0, 16, w * 4, 4, 0,
                        nullptr, nullptr, ah, t >= 1, hcb, lane, &parts[w][0][0]);
        }
        if (pb < 64 && v >= 2) {
          // final linear partials: out[t2][b=pb][i=lane], K split by wave
          const int t2 = v - 2;
          const _Float16* gsrc = g1r + (size_t)(t2 & 1) * 32768 + pb * 512;
          const _Float16* lrow = lWp + (size_t)lane * 512;
          float acc = 0.f;
          for (int ch = 0; ch < 16; ++ch) {
            const int k = w * 128 + ch * 8;
            H8 a, lw;
            a.q[0] = ald64(gsrc + k);
            a.q[1] = ald64(gsrc + k + 4);
            lw.u4 = *(const uint4*)(lrow + k);
#pragma unroll
            for (int j = 0; j < 8; ++j) acc += (float)a.h[j] * (float)lw.h[j];
          }
          outp[w][lane] = acc;
        }
      } else {
        if (v >= 1 && v <= 1024) {
          const int t = v - 1;
          const _Float16* ax = g0r + (size_t)(t & 1) * 32768 + (rb * 16 + m) * 512;
          const _Float16* ah = g1r + (size_t)((t - 1) & 1) * 32768 + (rb * 16 + m) * 512;
          tick_partials(wf3, 0, 1024, 2048, 2560, 32, 32, 16, 16, w * 8, 8, 16,
                        nullptr, ax, ah, t >= 1, hcb, lane, &parts[w][0][0]);
        }
      }
    }

    __syncthreads();  // bar1: all partials in LDS, all waves' stores drained

    // ---------------- EPILOGUE (wave 0) ----------------
    if (w == 0) {
      if (e >= E_ENC_BEG && e <= E_ENC_END) {
        const int u = e - E_ENC_BEG;
        if (isP0 && u <= 1023) {
          gru_epilogue(parts, quad, m, rb, hcb, br, bz, bx, bh, false,
                       gxr, gxz, gxn, hold, h0r + (size_t)(u & 1) * 32768);
        } else if (!isP0 && u >= 1) {
          gru_epilogue(parts, quad, m, rb, hcb, br, bz, bx, bh, false,
                       gxr, gxz, gxn, hold, h1r + (size_t)((u - 1) & 1) * 32768);
        }
      } else if (e == E_Z) {
        if (lane < 32) {
          const int b = bid >> 2, e0 = (bid & 3) * 32;
          const float s = outp[0][lane] + outp[1][lane] + outp[2][lane] +
                          outp[3][lane] + elb[e0 + lane];
          astf(&zbuf[b * 128 + e0 + lane], s);
        }
      } else if (e >= E_DEC_BEG) {
        const int v = e - E_DEC_BEG;
        if (isP0) {
          if (v <= 1023) {
            gru_epilogue(parts, quad, m, rb, hcb, br, bz, bx, bh, true,
                         gxr, gxz, gxn, hold, g0r + (size_t)(v & 1) * 32768);
          }
          if (pb < 64 && v >= 2) {
            const int t2 = v - 2;
            const float s = outp[0][lane] + outp[1][lane] + outp[2][lane] +
                            outp[3][lane] + dlb[lane];
            astf(&out[((size_t)t2 * 64 + pb) * 64 + lane], s);
          }
        } else {
          if (v >= 1 && v <= 1024) {
            gru_epilogue(parts, quad, m, rb, hcb, br, bz, bx, bh, false,
                         gxr, gxz, gxn, hold, g1r + (size_t)((v - 1) & 1) * 32768);
          }
        }
      }
      if (lane == 0) {
        // release: drains this wave's ring/out stores before publishing epoch
        __hip_atomic_store(&flags[bid], e, __ATOMIC_RELEASE, SC_AGT);
      }
    }

    __syncthreads();  // bar2: protect LDS reuse across epochs
  }
}

extern "C" void kernel_launch(void* const* d_in, const int* in_sizes, int n_in,
                              void* d_out, int out_size, void* d_ws, size_t ws_size,
                              hipStream_t stream) {
  (void)in_sizes; (void)n_in; (void)out_size; (void)ws_size;
  hipLaunchKernelGGL(gru_ae_kernel, dim3(256), dim3(256), 0, stream,
                     (const float*)d_in[0],
                     (const float*)d_in[1], (const float*)d_in[2],
                     (const float*)d_in[3], (const float*)d_in[4],
                     (const float*)d_in[5], (const float*)d_in[6],
                     (const float*)d_in[7], (const float*)d_in[8],
                     (const float*)d_in[9], (const float*)d_in[10],
                     (const float*)d_in[11], (const float*)d_in[12],
                     (const float*)d_in[13], (const float*)d_in[14],
                     (const float*)d_in[15], (const float*)d_in[16],
                     (const float*)d_in[17], (const float*)d_in[18],
                     (const float*)d_in[19], (const float*)d_in[20],
                     (float*)d_out, (char*)d_ws);
}

// Round 6
// 23837.007 us; speedup vs baseline: 1.6193x; 1.6193x over previous
//
#include <hip/hip_runtime.h>

// ============================================================================
// GRU autoencoder, single persistent kernel, MI355X (gfx950).  Round 6:
// round-1-verbatim data path (prepacked global weight fragments, full-grid
// lockstep epochs, wave0 epilogue) with a low-contention barrier:
//   - only wave 0 polls (others park on __syncthreads)
//   - per-block flags strided to one 64B line each (kills L3 line hotspot)
// ============================================================================

#define SC_AGT __HIP_MEMORY_SCOPE_AGENT

typedef _Float16 half8 __attribute__((ext_vector_type(8)));
typedef float floatx4 __attribute__((ext_vector_type(4)));

union H8 { unsigned long long q[2]; half8 h; uint4 u4; };
union HU { _Float16 f; unsigned short u; };

// ---- workspace layout (bytes) ----
static constexpr size_t OFF_FLAGS = 0;                        // 256 * 64B lines
static constexpr size_t OFF_Z     = 16384;                    // 64*128*4
static constexpr size_t OFF_GXC   = OFF_Z + 64 * 128 * 4;     // 64*1536*4
static constexpr size_t OFF_H0    = OFF_GXC + 64 * 1536 * 4;  // 2*64*512*2 each
static constexpr size_t OFF_H1    = OFF_H0 + 2 * 64 * 512 * 2;
static constexpr size_t OFF_G0    = OFF_H1 + 2 * 64 * 512 * 2;
static constexpr size_t OFF_G1    = OFF_G0 + 2 * 64 * 512 * 2;
static constexpr size_t OFF_LWP   = OFF_G1 + 2 * 64 * 512 * 2; // 64*512*2
static constexpr size_t OFF_WF    = OFF_LWP + 64 * 512 * 2;
// W-fragment store: unit = (gate,hcb,kc) = 2KB (hi plane 1KB + lo plane 1KB)
// layer unit counts: L0 1728, L1 3072, L2 1536, L3 3072  (total ~18.4 MB)

static constexpr int E_PREP    = 1;
static constexpr int E_ENC_BEG = 2;     // u = e-2, u in [0,1024]
static constexpr int E_ENC_END = 1026;
static constexpr int E_Z       = 1027;
static constexpr int E_GXC     = 1028;
static constexpr int E_DEC_BEG = 1029;  // v = e-1029, v in [0,1025]
static constexpr int E_LAST    = 2054;

__device__ __forceinline__ unsigned long long ald64(const void* p) {
  return __hip_atomic_load((const unsigned long long*)p, __ATOMIC_RELAXED, SC_AGT);
}
__device__ __forceinline__ int ald32(const int* p) {
  return __hip_atomic_load(p, __ATOMIC_RELAXED, SC_AGT);
}
__device__ __forceinline__ void ast16(void* p, unsigned short v) {
  __hip_atomic_store((unsigned short*)p, v, __ATOMIC_RELAXED, SC_AGT);
}
__device__ __forceinline__ void ast32u(void* p, unsigned int v) {
  __hip_atomic_store((unsigned int*)p, v, __ATOMIC_RELAXED, SC_AGT);
}
__device__ __forceinline__ void astf(float* p, float v) {
  __hip_atomic_store(p, v, __ATOMIC_RELAXED, SC_AGT);
}

__device__ __forceinline__ float sigm(float x) { return 1.f / (1.f + __expf(-x)); }
__device__ __forceinline__ float tanh_f(float x) {
  x = fminf(fmaxf(x, -30.f), 30.f);
  const float e2 = __expf(2.f * x);
  return (e2 - 1.f) / (e2 + 1.f);
}

#define MFMA(a, b, c) __builtin_amdgcn_mfma_f32_16x16x32_f16((a), (b), (c), 0, 0, 0)

// full-grid barrier wait, wave0 only: lane i polls block flags i, i+64,
// i+128, i+192 -- each flag on its own 64B line (flags[bid*16]).
__device__ __forceinline__ void pollwait(const int* flags, int target) {
  const int lane = threadIdx.x & 63;
  for (;;) {
    const int v0 = ald32(flags + (size_t)lane * 16);
    const int v1 = ald32(flags + (size_t)(64 + lane) * 16);
    const int v2 = ald32(flags + (size_t)(128 + lane) * 16);
    const int v3 = ald32(flags + (size_t)(192 + lane) * 16);
    const bool ok = (v0 >= target) && (v1 >= target) && (v2 >= target) &&
                    (v3 >= target);
    if (__ballot(ok) == ~0ull) break;
    __builtin_amdgcn_s_sleep(2);
  }
  asm volatile("" ::: "memory");
}

// One GRU step partial-GEMM for this wave's K-slice (round-1 verbatim).
__device__ __forceinline__ void tick_partials(
    const char* __restrict__ wf,
    int g0u, int g1u, int g2u, int g3u,
    int nk0, int nk1, int nk2, int nk3,
    int kc0, int kccnt, int hsplit,
    const float* __restrict__ xs,
    const _Float16* __restrict__ ax,
    const _Float16* __restrict__ ah,
    bool hvalid, int hcb, int lane,
    float* __restrict__ partsW) {
  const int quad = lane >> 4;
  H8 A[8];
#pragma unroll
  for (int c = 0; c < 8; ++c) {
    A[c].q[0] = 0ull;
    A[c].q[1] = 0ull;
    if (c < kccnt) {
      const int kc = kc0 + c;
      if (kc < hsplit) {
        if (xs) {
          const float* p = xs + kc * 32 + quad * 8;
          const float4 f0 = *(const float4*)p;
          const float4 f1 = *(const float4*)(p + 4);
          H8 t;
          t.h[0] = (_Float16)f0.x; t.h[1] = (_Float16)f0.y;
          t.h[2] = (_Float16)f0.z; t.h[3] = (_Float16)f0.w;
          t.h[4] = (_Float16)f1.x; t.h[5] = (_Float16)f1.y;
          t.h[6] = (_Float16)f1.z; t.h[7] = (_Float16)f1.w;
          A[c] = t;
        } else {
          const _Float16* p = ax + kc * 32 + quad * 8;
          A[c].q[0] = ald64(p);
          A[c].q[1] = ald64(p + 4);
        }
      } else if (hvalid) {
        const _Float16* p = ah + (kc - hsplit) * 32 + quad * 8;
        A[c].q[0] = ald64(p);
        A[c].q[1] = ald64(p + 4);
      }
    }
  }
  floatx4 ar = {0.f, 0.f, 0.f, 0.f};
  floatx4 az = ar, axn = ar, ahn = ar;
  const size_t lb = (size_t)lane * 16;
#pragma unroll
  for (int c = 0; c < 8; ++c) {
    if (c < kccnt) {
      const int kc = kc0 + c;
      const bool inH = (kc >= hsplit);
      if (!inH || hvalid) {
        {
          const char* b = wf + (size_t)(g0u + hcb * nk0 + kc) * 2048 + lb;
          H8 whi, wlo;
          whi.u4 = *(const uint4*)b;
          wlo.u4 = *(const uint4*)(b + 1024);
          ar = MFMA(A[c].h, whi.h, ar);
          ar = MFMA(A[c].h, wlo.h, ar);
        }
        {
          const char* b = wf + (size_t)(g1u + hcb * nk1 + kc) * 2048 + lb;
          H8 whi, wlo;
          whi.u4 = *(const uint4*)b;
          wlo.u4 = *(const uint4*)(b + 1024);
          az = MFMA(A[c].h, whi.h, az);
          az = MFMA(A[c].h, wlo.h, az);
        }
        if (!inH) {
          const char* b = wf + (size_t)(g2u + hcb * nk2 + kc) * 2048 + lb;
          H8 whi, wlo;
          whi.u4 = *(const uint4*)b;
          wlo.u4 = *(const uint4*)(b + 1024);
          axn = MFMA(A[c].h, whi.h, axn);
          axn = MFMA(A[c].h, wlo.h, axn);
        } else {
          const char* b = wf + (size_t)(g3u + hcb * nk3 + (kc - hsplit)) * 2048 + lb;
          H8 whi, wlo;
          whi.u4 = *(const uint4*)b;
          wlo.u4 = *(const uint4*)(b + 1024);
          ahn = MFMA(A[c].h, whi.h, ahn);
          ahn = MFMA(A[c].h, wlo.h, ahn);
        }
      }
    }
  }
  const int m = lane & 15;
#pragma unroll
  for (int i = 0; i < 4; ++i) {
    const int idx = (quad * 4 + i) * 16 + m;
    partsW[0 * 256 + idx] = ar[i];
    partsW[1 * 256 + idx] = az[i];
    partsW[2 * 256 + idx] = axn[i];
    partsW[3 * 256 + idx] = ahn[i];
  }
}

// wave0 epilogue (round-1 verbatim)
__device__ __forceinline__ void gru_epilogue(
    const float (*__restrict__ P)[4][256],
    int quad, int m, int rb, int hcb,
    float br, float bz, float bx, float bh,
    bool dec0, const float* gxr, const float* gxz, const float* gxn,
    float* hold, _Float16* __restrict__ ring) {
#pragma unroll
  for (int i = 0; i < 4; ++i) {
    const int idx = (quad * 4 + i) * 16 + m;
    const float sr = P[0][0][idx] + P[1][0][idx] + P[2][0][idx] + P[3][0][idx];
    const float sz = P[0][1][idx] + P[1][1][idx] + P[2][1][idx] + P[3][1][idx];
    const float sx = P[0][2][idx] + P[1][2][idx] + P[2][2][idx] + P[3][2][idx];
    const float sh = P[0][3][idx] + P[1][3][idx] + P[2][3][idx] + P[3][3][idx];
    float pr, pz, px;
    if (dec0) { pr = sr + gxr[i] + br; pz = sz + gxz[i] + bz; px = gxn[i]; }
    else      { pr = sr + br;          pz = sz + bz;          px = sx + bx; }
    const float r = sigm(pr);
    const float z = sigm(pz);
    const float n = tanh_f(px + r * (sh + bh));
    const float hh = (1.f - z) * n + z * hold[i];
    hold[i] = hh;
    HU cv;
    cv.f = (_Float16)hh;
    ast16(ring + (rb * 16 + quad * 4 + i) * 512 + hcb * 16 + m, cv.u);
  }
}

extern "C" __global__ void __launch_bounds__(256, 1) gru_ae_kernel(
    const float* __restrict__ x,
    const float* __restrict__ eW0i, const float* __restrict__ eW0h,
    const float* __restrict__ eb0i, const float* __restrict__ eb0h,
    const float* __restrict__ eW1i, const float* __restrict__ eW1h,
    const float* __restrict__ eb1i, const float* __restrict__ eb1h,
    const float* __restrict__ elW, const float* __restrict__ elb,
    const float* __restrict__ dW0i, const float* __restrict__ dW0h,
    const float* __restrict__ db0i, const float* __restrict__ db0h,
    const float* __restrict__ dW1i, const float* __restrict__ dW1h,
    const float* __restrict__ db1i, const float* __restrict__ db1h,
    const float* __restrict__ dlW, const float* __restrict__ dlb,
    float* __restrict__ out, char* __restrict__ ws) {
  const int tid = threadIdx.x, bid = blockIdx.x;
  const int lane = tid & 63, w = tid >> 6;
  const int quad = lane >> 4, m = lane & 15;
  const bool isP0 = bid < 128;
  const int pb = isP0 ? bid : bid - 128;
  const int rb = pb >> 5, hcb = pb & 31;

  int* flags = (int*)(ws + OFF_FLAGS);
  float* zbuf = (float*)(ws + OFF_Z);
  float* gxc = (float*)(ws + OFF_GXC);
  _Float16* h0r = (_Float16*)(ws + OFF_H0);
  _Float16* h1r = (_Float16*)(ws + OFF_H1);
  _Float16* g0r = (_Float16*)(ws + OFF_G0);
  _Float16* g1r = (_Float16*)(ws + OFF_G1);
  _Float16* lWp = (_Float16*)(ws + OFF_LWP);
  const char* wfb = ws + OFF_WF;
  const char* wf0 = wfb;
  const char* wf1 = wfb + (size_t)1728 * 2048;
  const char* wf2 = wfb + (size_t)(1728 + 3072) * 2048;
  const char* wf3 = wfb + (size_t)(1728 + 3072 + 1536) * 2048;

  __shared__ float parts[4][4][256];
  __shared__ float outp[4][64];

  float hold[4] = {0.f, 0.f, 0.f, 0.f};
  float br = 0.f, bz = 0.f, bx = 0.f, bh = 0.f;
  float gxr[4] = {0, 0, 0, 0}, gxz[4] = {0, 0, 0, 0}, gxn[4] = {0, 0, 0, 0};

  for (int e = E_PREP; e <= E_LAST; ++e) {
    if (e > E_PREP) {
      if (w == 0) pollwait(flags, e - 1);
      __syncthreads();  // release other waves once w0 has seen the epoch
    }

    // ---------------- WORK (all waves) ----------------
    if (e == E_PREP) {
      // pack weights: fp16 hi/lo planes, MFMA-fragment ordered
      const int uend[4] = {1728, 4800, 6336, 9408};
      const int gub_[4][4] = {{0, 576, 1152, 1216}, {0, 1024, 2048, 2560},
                              {0, 512, 1024, 1024}, {0, 1024, 2048, 2560}};
      const int nkc_[4][4] = {{18, 18, 2, 16}, {32, 32, 16, 16},
                              {16, 16, 0, 16}, {32, 32, 16, 16}};
      const size_t wbL[4] = {0, (size_t)1728 * 2048, (size_t)4800 * 2048,
                             (size_t)6336 * 2048};
      const int wgid = bid * 4 + w;
      for (int unit = wgid; unit < 9408; unit += 1024) {
        int L = 0, lu = unit;
        if (unit >= uend[2]) { L = 3; lu = unit - uend[2]; }
        else if (unit >= uend[1]) { L = 2; lu = unit - uend[1]; }
        else if (unit >= uend[0]) { L = 1; lu = unit - uend[0]; }
        int g;
        if (lu < gub_[L][1]) g = 0;
        else if (lu < gub_[L][2]) g = 1;
        else if (nkc_[L][2] > 0 && lu < gub_[L][3]) g = 2;
        else g = 3;
        const int r2 = lu - gub_[L][g];
        const int nk = nkc_[L][g];
        const int hcbp = r2 / nk, kcp = r2 % nk;
        const int colp = hcbp * 16 + m;
        const float *Wi, *Wh;
        int Din;
        if (L == 0)      { Wi = eW0i; Wh = eW0h; Din = 64; }
        else if (L == 1) { Wi = eW1i; Wh = eW1h; Din = 512; }
        else if (L == 2) { Wi = nullptr; Wh = dW0h; Din = 0; }
        else             { Wi = dW1i; Wh = dW1h; Din = 512; }
        char* ub = (char*)(ws + OFF_WF) + wbL[L] + (size_t)lu * 2048 + lane * 16;
#pragma unroll
        for (int jj = 0; jj < 4; ++jj) {
          unsigned int hiw = 0, low = 0;
#pragma unroll
          for (int j2 = 0; j2 < 2; ++j2) {
            const int j = jj * 2 + j2;
            const int k = kcp * 32 + quad * 8 + j;
            float wv;
            if (g <= 1) {
              if (Wi && k < Din) wv = Wi[(size_t)(g * 512 + colp) * Din + k];
              else wv = Wh[(size_t)(g * 512 + colp) * 512 + (k - (Wi ? Din : 0))];
            } else if (g == 2) {
              wv = Wi[(size_t)(1024 + colp) * Din + k];
            } else {
              wv = Wh[(size_t)(1024 + colp) * 512 + k];
            }
            HU hi, lo;
            hi.f = (_Float16)wv;
            lo.f = (_Float16)(wv - (float)hi.f);
            hiw |= ((unsigned int)hi.u) << (16 * j2);
            low |= ((unsigned int)lo.u) << (16 * j2);
          }
          ast32u(ub + jj * 4, hiw);
          ast32u(ub + 1024 + jj * 4, low);
        }
      }
      // pack final-linear weight fp16
      const int gid = bid * 256 + tid;
      if (gid < 32768) {
        HU cv;
        cv.f = (_Float16)dlW[gid];
        ast16(lWp + gid, cv.u);
      }
    } else if (e <= E_ENC_END) {
      const int u = e - E_ENC_BEG;
      if (e == E_ENC_BEG) {
        const int colg = hcb * 16 + m;
        if (isP0) {
          br = eb0i[colg] + eb0h[colg];
          bz = eb0i[512 + colg] + eb0h[512 + colg];
          bx = eb0i[1024 + colg];
          bh = eb0h[1024 + colg];
        } else {
          br = eb1i[colg] + eb1h[colg];
          bz = eb1i[512 + colg] + eb1h[512 + colg];
          bx = eb1i[1024 + colg];
          bh = eb1h[1024 + colg];
        }
        hold[0] = hold[1] = hold[2] = hold[3] = 0.f;
      }
      if (isP0) {
        if (u <= 1023) {
          const int t = u;
          const float* xs = x + ((size_t)t * 64 + rb * 16 + m) * 64;
          const _Float16* ah = h0r + (size_t)((t - 1) & 1) * 32768 + (rb * 16 + m) * 512;
          const int kc0 = (w == 0) ? 0 : (w == 1) ? 5 : (w == 2) ? 10 : 14;
          const int cnt = (w < 2) ? 5 : 4;
          tick_partials(wf0, 0, 576, 1152, 1216, 18, 18, 2, 16, kc0, cnt, 2,
                        xs, nullptr, ah, t >= 1, hcb, lane, &parts[w][0][0]);
        }
      } else {
        if (u >= 1) {
          const int t = u - 1;
          const _Float16* ax = h0r + (size_t)(t & 1) * 32768 + (rb * 16 + m) * 512;
          const _Float16* ah = h1r + (size_t)((t - 1) & 1) * 32768 + (rb * 16 + m) * 512;
          tick_partials(wf1, 0, 1024, 2048, 2560, 32, 32, 16, 16, w * 8, 8, 16,
                        nullptr, ax, ah, t >= 1, hcb, lane, &parts[w][0][0]);
        }
      }
    } else if (e == E_Z) {
      const int b = bid >> 2, e0 = (bid & 3) * 32;
      float acc = 0.f;
      if (lane < 32) {
        const _Float16* hsrc = h1r + (size_t)1 * 32768 + b * 512;  // h1[1023]
        const float* lwrow = elW + (size_t)(e0 + lane) * 512;
        for (int ch = 0; ch < 16; ++ch) {
          const int k = w * 128 + ch * 8;
          H8 a;
          a.q[0] = ald64(hsrc + k);
          a.q[1] = ald64(hsrc + k + 4);
          const float4 l0 = *(const float4*)(lwrow + k);
          const float4 l1 = *(const float4*)(lwrow + k + 4);
          acc += (float)a.h[0] * l0.x + (float)a.h[1] * l0.y +
                 (float)a.h[2] * l0.z + (float)a.h[3] * l0.w +
                 (float)a.h[4] * l1.x + (float)a.h[5] * l1.y +
                 (float)a.h[6] * l1.z + (float)a.h[7] * l1.w;
        }
      }
      outp[w][lane] = acc;
    } else if (e == E_GXC) {
      const int b = bid & 63, cb = (bid >> 6) * 384;
      for (int idx = w * 64 + lane; idx < 384; idx += 256) {
        const int c = cb + idx;
        float acc = db0i[c];
        const float* zr = zbuf + b * 128;
        const float* wr = dW0i + (size_t)c * 128;
        for (int k = 0; k < 128; ++k) acc += zr[k] * wr[k];
        astf(&gxc[(size_t)b * 1536 + c], acc);
      }
    } else {
      const int v = e - E_DEC_BEG;
      if (e == E_DEC_BEG) {
        const int colg = hcb * 16 + m;
        if (isP0) {
          br = db0h[colg];
          bz = db0h[512 + colg];
          bx = 0.f;
          bh = db0h[1024 + colg];
#pragma unroll
          for (int i = 0; i < 4; ++i) {
            const int row = rb * 16 + quad * 4 + i;
            gxr[i] = gxc[(size_t)row * 1536 + colg];
            gxz[i] = gxc[(size_t)row * 1536 + 512 + colg];
            gxn[i] = gxc[(size_t)row * 1536 + 1024 + colg];
          }
        } else {
          br = db1i[colg] + db1h[colg];
          bz = db1i[512 + colg] + db1h[512 + colg];
          bx = db1i[1024 + colg];
          bh = db1h[1024 + colg];
        }
        hold[0] = hold[1] = hold[2] = hold[3] = 0.f;
      }
      if (isP0) {
        if (v <= 1023) {
          const int t = v;
          const _Float16* ah = g0r + (size_t)((t - 1) & 1) * 32768 + (rb * 16 + m) * 512;
          tick_partials(wf2, 0, 512, 0, 1024, 16, 16, 0, 16, w * 4, 4, 0,
                        nullptr, nullptr, ah, t >= 1, hcb, lane, &parts[w][0][0]);
        }
        if (pb < 64 && v >= 2) {
          // final linear partials: out[t2][b=pb][i=lane], K split by wave
          const int t2 = v - 2;
          const _Float16* gsrc = g1r + (size_t)(t2 & 1) * 32768 + pb * 512;
          const _Float16* lrow = lWp + (size_t)lane * 512;
          float acc = 0.f;
          for (int ch = 0; ch < 16; ++ch) {
            const int k = w * 128 + ch * 8;
            H8 a, lw;
            a.q[0] = ald64(gsrc + k);
            a.q[1] = ald64(gsrc + k + 4);
            lw.u4 = *(const uint4*)(lrow + k);
#pragma unroll
            for (int j = 0; j < 8; ++j) acc += (float)a.h[j] * (float)lw.h[j];
          }
          outp[w][lane] = acc;
        }
      } else {
        if (v >= 1 && v <= 1024) {
          const int t = v - 1;
          const _Float16* ax = g0r + (size_t)(t & 1) * 32768 + (rb * 16 + m) * 512;
          const _Float16* ah = g1r + (size_t)((t - 1) & 1) * 32768 + (rb * 16 + m) * 512;
          tick_partials(wf3, 0, 1024, 2048, 2560, 32, 32, 16, 16, w * 8, 8, 16,
                        nullptr, ax, ah, t >= 1, hcb, lane, &parts[w][0][0]);
        }
      }
    }

    __syncthreads();  // bar1: all partials in LDS, all waves' stores drained

    // ---------------- EPILOGUE (wave 0) ----------------
    if (w == 0) {
      if (e >= E_ENC_BEG && e <= E_ENC_END) {
        const int u = e - E_ENC_BEG;
        if (isP0 && u <= 1023) {
          gru_epilogue(parts, quad, m, rb, hcb, br, bz, bx, bh, false,
                       gxr, gxz, gxn, hold, h0r + (size_t)(u & 1) * 32768);
        } else if (!isP0 && u >= 1) {
          gru_epilogue(parts, quad, m, rb, hcb, br, bz, bx, bh, false,
                       gxr, gxz, gxn, hold, h1r + (size_t)((u - 1) & 1) * 32768);
        }
      } else if (e == E_Z) {
        if (lane < 32) {
          const int b = bid >> 2, e0 = (bid & 3) * 32;
          const float s = outp[0][lane] + outp[1][lane] + outp[2][lane] +
                          outp[3][lane] + elb[e0 + lane];
          astf(&zbuf[b * 128 + e0 + lane], s);
        }
      } else if (e >= E_DEC_BEG) {
        const int v = e - E_DEC_BEG;
        if (isP0) {
          if (v <= 1023) {
            gru_epilogue(parts, quad, m, rb, hcb, br, bz, bx, bh, true,
                         gxr, gxz, gxn, hold, g0r + (size_t)(v & 1) * 32768);
          }
          if (pb < 64 && v >= 2) {
            const int t2 = v - 2;
            const float s = outp[0][lane] + outp[1][lane] + outp[2][lane] +
                            outp[3][lane] + dlb[lane];
            astf(&out[((size_t)t2 * 64 + pb) * 64 + lane], s);
          }
        } else {
          if (v >= 1 && v <= 1024) {
            gru_epilogue(parts, quad, m, rb, hcb, br, bz, bx, bh, false,
                         gxr, gxz, gxn, hold, g1r + (size_t)((v - 1) & 1) * 32768);
          }
        }
      }
      if (lane == 0) {
        // release: drains this wave's ring/out stores before publishing epoch
        __hip_atomic_store(&flags[bid * 16], e, __ATOMIC_RELEASE, SC_AGT);
      }
    }

    __syncthreads();  // bar2: protect LDS reuse across epochs
  }
}

extern "C" void kernel_launch(void* const* d_in, const int* in_sizes, int n_in,
                              void* d_out, int out_size, void* d_ws, size_t ws_size,
                              hipStream_t stream) {
  (void)in_sizes; (void)n_in; (void)out_size; (void)ws_size;
  hipMemsetAsync(d_ws, 0, 16384, stream);  // zero strided epoch flags
  hipLaunchKernelGGL(gru_ae_kernel, dim3(256), dim3(256), 0, stream,
                     (const float*)d_in[0],
                     (const float*)d_in[1], (const float*)d_in[2],
                     (const float*)d_in[3], (const float*)d_in[4],
                     (const float*)d_in[5], (const float*)d_in[6],
                     (const float*)d_in[7], (const float*)d_in[8],
                     (const float*)d_in[9], (const float*)d_in[10],
                     (const float*)d_in[11], (const float*)d_in[12],
                     (const float*)d_in[13], (const float*)d_in[14],
                     (const float*)d_in[15], (const float*)d_in[16],
                     (const float*)d_in[17], (const float*)d_in[18],
                     (const float*)d_in[19], (const float*)d_in[20],
                     (float*)d_out, (char*)d_ws);
}